// Round 12
// baseline (293.465 us; speedup 1.0000x reference)
//
#include <hip/hip_runtime.h>
#include <hip/hip_bf16.h>
#include <stdint.h>

#define NN 100000
#define EE 1600000
#define NBUCK 196              // ceil(NN/512): buckets of 512 dst nodes
#define CSB 512                // coarse-scatter blocks

typedef __attribute__((ext_vector_type(4))) float f32x4;
typedef __attribute__((ext_vector_type(8))) short bf16x8;

__device__ inline ushort f2bf(float f) {
    union { float f; uint32_t u; } v; v.f = f;
    uint32_t u = v.u;
    uint32_t r = (u + 0x7fffu + ((u >> 16) & 1u)) >> 16;   // RNE
    return (ushort)r;
}
__device__ inline float bflo(uint32_t u) {
    union { uint32_t u; float f; } v; v.u = u << 16; return v.f;
}
__device__ inline float bfhi(uint32_t u) {
    union { uint32_t u; float f; } v; v.u = u & 0xffff0000u; return v.f;
}

// ---------------- fused prep: detect dtype + bf16 conversions + zero counters ----
__global__ __launch_bounds__(256) void prep_kernel(
    const float* __restrict__ x, const unsigned int* __restrict__ raw,
    const float* __restrict__ Wl1, const float* __restrict__ Wr1,
    const float* __restrict__ Wl2, const float* __restrict__ Wr2,
    ushort* __restrict__ xb, ushort* __restrict__ wc1, ushort* __restrict__ wc2,
    int* __restrict__ flag, int* __restrict__ ccnt, int* __restrict__ cfill)
{
    const int gid = blockIdx.x * 256 + threadIdx.x;
    const int stride = gridDim.x * 256;

    // dtype detect on first 4096 int64 slots
    if (gid < 4096) {
        if (raw[2 * gid + 1] != 0u) atomicOr(flag, 1);
    }
    // zero bucket counters
    if (gid >= 4096 && gid < 4096 + NBUCK) ccnt[gid - 4096] = 0;
    if (gid >= 4096 + NBUCK && gid < 4096 + 2 * NBUCK) cfill[gid - 4096 - NBUCK] = 0;

    // x -> bf16 (one float4 per iter)
    const int n4 = NN * 64 / 4;
    for (int i = gid; i < n4; i += stride) {
        float4 v = *(const float4*)&x[i * 4];
        ushort o[4] = { f2bf(v.x), f2bf(v.y), f2bf(v.z), f2bf(v.w) };
        *(uint64_t*)&xb[i * 4] = *(const uint64_t*)o;
    }
    // Wcat1 (K=64): wc1[o][0..64)=Wl1, [64..128)=Wr1
    for (int i = gid; i < 128 * 128; i += stride) {
        int o = i >> 7, k = i & 127;
        float v = (k < 64) ? Wl1[o * 64 + k] : Wr1[o * 64 + (k - 64)];
        wc1[o * 128 + k] = f2bf(v);
    }
    // Wcat2 (K=128)
    for (int i = gid; i < 128 * 256; i += stride) {
        int o = i >> 8, k = i & 255;
        float v = (k < 128) ? Wl2[o * 128 + k] : Wr2[o * 128 + (k - 128)];
        wc2[o * 256 + k] = f2bf(v);
    }
}

// ---------------- CSR build: two-level partition (block-reserved) ----------------
__global__ __launch_bounds__(256) void coarse_hist(const void* raw, const int* flag,
                                                   int* ccnt, int E) {
    __shared__ int lh[NBUCK];
    for (int i = threadIdx.x; i < NBUCK; i += 256) lh[i] = 0;
    __syncthreads();
    int stride = gridDim.x * 256;
    if (*flag) {
        const int* p = (const int*)raw;
        for (int e = blockIdx.x * 256 + threadIdx.x; e < E; e += stride)
            atomicAdd(&lh[p[E + e] >> 9], 1);
    } else {
        const long long* p = (const long long*)raw;
        for (int e = blockIdx.x * 256 + threadIdx.x; e < E; e += stride)
            atomicAdd(&lh[((int)p[E + e]) >> 9], 1);
    }
    __syncthreads();
    for (int i = threadIdx.x; i < NBUCK; i += 256)
        if (lh[i]) atomicAdd(&ccnt[i], lh[i]);
}

__global__ void coarse_scan(const int* ccnt, int* coff, int* offsets, int E) {
    __shared__ int part[256];
    int t = threadIdx.x;
    int v[4]; int s = 0;
    #pragma unroll
    for (int j = 0; j < 4; j++) {
        int i = t * 4 + j;
        v[j] = (i < NBUCK) ? ccnt[i] : 0;
        s += v[j];
    }
    part[t] = s; __syncthreads();
    for (int off = 1; off < 256; off <<= 1) {
        int add = (t >= off) ? part[t - off] : 0;
        __syncthreads();
        part[t] += add;
        __syncthreads();
    }
    int run = part[t] - s;
    #pragma unroll
    for (int j = 0; j < 4; j++) {
        int i = t * 4 + j;
        if (i <= NBUCK) coff[i] = run;
        run += v[j];
    }
    if (t == 0) offsets[NN] = E;
}

__global__ __launch_bounds__(256) void coarse_scatter2(const void* raw, const int* flag,
                                                       const int* coff, int* cfill,
                                                       uint32_t* pbuf, int E) {
    __shared__ int lh[NBUCK];
    __shared__ int gbase[NBUCK];
    __shared__ int lfill[NBUCK];
    const int t = threadIdx.x;
    for (int i = t; i < NBUCK; i += 256) { lh[i] = 0; lfill[i] = 0; }
    __syncthreads();
    const int chunk = (E + (int)gridDim.x - 1) / (int)gridDim.x;
    const int s0 = blockIdx.x * chunk;
    const int s1 = min(E, s0 + chunk);
    const bool is32 = (*flag != 0);
    if (is32) {
        const int* p = (const int*)raw;
        for (int e = s0 + t; e < s1; e += 256) atomicAdd(&lh[p[E + e] >> 9], 1);
    } else {
        const long long* p = (const long long*)raw;
        for (int e = s0 + t; e < s1; e += 256) atomicAdd(&lh[((int)p[E + e]) >> 9], 1);
    }
    __syncthreads();
    for (int i = t; i < NBUCK; i += 256)
        gbase[i] = coff[i] + (lh[i] ? atomicAdd(&cfill[i], lh[i]) : 0);
    __syncthreads();
    if (is32) {
        const int* p = (const int*)raw;
        for (int e = s0 + t; e < s1; e += 256) {
            int sr = p[e], d = p[E + e];
            int b = d >> 9;
            int r = atomicAdd(&lfill[b], 1);
            pbuf[gbase[b] + r] = ((uint32_t)(d & 511) << 17) | (uint32_t)sr;
        }
    } else {
        const long long* p = (const long long*)raw;
        for (int e = s0 + t; e < s1; e += 256) {
            int sr = (int)p[e], d = (int)p[E + e];
            int b = d >> 9;
            int r = atomicAdd(&lfill[b], 1);
            pbuf[gbase[b] + r] = ((uint32_t)(d & 511) << 17) | (uint32_t)sr;
        }
    }
}

__global__ __launch_bounds__(512) void fine_bucket(const uint32_t* __restrict__ pbuf,
                                                   const int* __restrict__ coff,
                                                   int* __restrict__ offsets,
                                                   int* __restrict__ srcs_sort, int N) {
    __shared__ int cnt[512], sc[512], fil[512];
    const int b = blockIdx.x, t = threadIdx.x;
    const int s = coff[b], e = coff[b + 1];
    cnt[t] = 0; fil[t] = 0;
    __syncthreads();
    for (int i = s + t; i < e; i += 512) atomicAdd(&cnt[pbuf[i] >> 17], 1);
    __syncthreads();
    sc[t] = cnt[t];
    __syncthreads();
    for (int off = 1; off < 512; off <<= 1) {
        int add = (t >= off) ? sc[t - off] : 0;
        __syncthreads();
        sc[t] += add;
        __syncthreads();
    }
    const int nb0 = b * 512;
    if (nb0 + t < N) offsets[nb0 + t] = s + sc[t] - cnt[t];
    for (int i = s + t; i < e; i += 512) {
        uint32_t p = pbuf[i];
        int dl = (int)(p >> 17);
        int sr = (int)(p & 0x1FFFFu);
        int pos = s + (sc[dl] - cnt[dl]) + atomicAdd(&fil[dl], 1);
        srcs_sort[pos] = sr;
    }
    __syncthreads();     // all scatters of this bucket visible (same block)
    // per-node insertion sort by src: aligns concurrent waves' gather sweeps
    // (locality experiment; order is irrelevant to the mean itself)
    {
        int a  = s + sc[t] - cnt[t];
        int e2 = a + cnt[t];
        for (int i = a + 1; i < e2; i++) {
            int v = srcs_sort[i];
            int j = i - 1;
            while (j >= a && srcs_sort[j] > v) { srcs_sort[j + 1] = srcs_sort[j]; j--; }
            srcs_sort[j + 1] = v;
        }
    }
}

// ---------------- FUSED aggregate + SAGE linear ----------------
// Block = 4 waves = 32 nodes (N % 32 == 0).
// Phase 1 (node-per-quarter-wave): each 16-lane quarter owns one node's edge
//   stream (src-sorted); lane covers K/16 channels, one 16B/8B load per edge.
// Phase 2: 32x128 GEMM from LDS (swapped-operand MFMA, contiguous stores).
template<int K, bool RELU, bool OUT_BF16>
__global__ __launch_bounds__(256) void sage_fused(
    const int* __restrict__ offsets, const int* __restrict__ srcs,
    const ushort* __restrict__ xin, const ushort* __restrict__ Wcat,
    const float* __restrict__ bl, void* __restrict__ outv, int N)
{
    constexpr int KT = 2 * K;
    constexpr int RP = K + 8;                 // padded row (ushorts)
    __shared__ ushort mlds[32][RP];
    __shared__ ushort slds[32][RP];
    const int t = threadIdx.x;
    const int w = t >> 6;
    const int lane = t & 63;
    const int nb = blockIdx.x * 32;

    // stage self rows (coalesced 16B chunks)
    #pragma unroll
    for (int idx = t; idx < 32 * (K / 8); idx += 256) {
        int r = idx / (K / 8), c = idx % (K / 8);
        *(uint4*)&slds[r][c * 8] = *(const uint4*)&xin[(size_t)(nb + r) * K + c * 8];
    }

    const int q     = lane >> 4;              // quarter 0-3
    const int ql    = lane & 15;
    const int qbase = lane & 48;              // shfl base of own quarter

    // batch-load the 9 offsets this wave needs
    int offv = 0;
    if (lane < 9) offv = offsets[nb + w * 8 + lane];

    // phase 1: 2 passes x 4 quarters = 8 nodes per wave
    for (int pi = 0; pi < 2; pi++) {
        const int ln = w * 8 + pi * 4 + q;            // local node index
        const int s0 = __shfl(offv, pi * 4 + q);
        const int s1 = __shfl(offv, pi * 4 + q + 1);
        const float inv = 1.0f / fmaxf((float)(s1 - s0), 1.0f);

        if (K == 64) {
            float f0=0.f, f1=0.f, f2=0.f, f3=0.f;
            for (int base = s0; base < s1; base += 16) {
                int cnt = min(16, s1 - base);
                int myidx = (base + ql < s1) ? srcs[base + ql] : 0;
                int j = 0;
                for (; j + 4 <= cnt; j += 4) {
                    int sA = __shfl(myidx, qbase + j);
                    int sB = __shfl(myidx, qbase + j + 1);
                    int sC = __shfl(myidx, qbase + j + 2);
                    int sD = __shfl(myidx, qbase + j + 3);
                    uint2 uA = *(const uint2*)&xin[(size_t)sA * 64 + ql * 4];
                    uint2 uB = *(const uint2*)&xin[(size_t)sB * 64 + ql * 4];
                    uint2 uC = *(const uint2*)&xin[(size_t)sC * 64 + ql * 4];
                    uint2 uD = *(const uint2*)&xin[(size_t)sD * 64 + ql * 4];
                    f0 += bflo(uA.x); f1 += bfhi(uA.x); f2 += bflo(uA.y); f3 += bfhi(uA.y);
                    f0 += bflo(uB.x); f1 += bfhi(uB.x); f2 += bflo(uB.y); f3 += bfhi(uB.y);
                    f0 += bflo(uC.x); f1 += bfhi(uC.x); f2 += bflo(uC.y); f3 += bfhi(uC.y);
                    f0 += bflo(uD.x); f1 += bfhi(uD.x); f2 += bflo(uD.y); f3 += bfhi(uD.y);
                }
                for (; j < cnt; j++) {
                    int s = __shfl(myidx, qbase + j);
                    uint2 u = *(const uint2*)&xin[(size_t)s * 64 + ql * 4];
                    f0 += bflo(u.x); f1 += bfhi(u.x); f2 += bflo(u.y); f3 += bfhi(u.y);
                }
            }
            ushort o[4] = { f2bf(f0 * inv), f2bf(f1 * inv), f2bf(f2 * inv), f2bf(f3 * inv) };
            *(uint64_t*)&mlds[ln][ql * 4] = *(const uint64_t*)o;
        } else {
            float f0=0.f, f1=0.f, f2=0.f, f3=0.f, f4=0.f, f5=0.f, f6=0.f, f7=0.f;
            for (int base = s0; base < s1; base += 16) {
                int cnt = min(16, s1 - base);
                int myidx = (base + ql < s1) ? srcs[base + ql] : 0;
                int j = 0;
                for (; j + 4 <= cnt; j += 4) {
                    int sA = __shfl(myidx, qbase + j);
                    int sB = __shfl(myidx, qbase + j + 1);
                    int sC = __shfl(myidx, qbase + j + 2);
                    int sD = __shfl(myidx, qbase + j + 3);
                    uint4 uA = *(const uint4*)&xin[(size_t)sA * 128 + ql * 8];
                    uint4 uB = *(const uint4*)&xin[(size_t)sB * 128 + ql * 8];
                    uint4 uC = *(const uint4*)&xin[(size_t)sC * 128 + ql * 8];
                    uint4 uD = *(const uint4*)&xin[(size_t)sD * 128 + ql * 8];
                    f0 += bflo(uA.x); f1 += bfhi(uA.x); f2 += bflo(uA.y); f3 += bfhi(uA.y);
                    f4 += bflo(uA.z); f5 += bfhi(uA.z); f6 += bflo(uA.w); f7 += bfhi(uA.w);
                    f0 += bflo(uB.x); f1 += bfhi(uB.x); f2 += bflo(uB.y); f3 += bfhi(uB.y);
                    f4 += bflo(uB.z); f5 += bfhi(uB.z); f6 += bflo(uB.w); f7 += bfhi(uB.w);
                    f0 += bflo(uC.x); f1 += bfhi(uC.x); f2 += bflo(uC.y); f3 += bfhi(uC.y);
                    f4 += bflo(uC.z); f5 += bfhi(uC.z); f6 += bflo(uC.w); f7 += bfhi(uC.w);
                    f0 += bflo(uD.x); f1 += bfhi(uD.x); f2 += bflo(uD.y); f3 += bfhi(uD.y);
                    f4 += bflo(uD.z); f5 += bfhi(uD.z); f6 += bflo(uD.w); f7 += bfhi(uD.w);
                }
                for (; j < cnt; j++) {
                    int s = __shfl(myidx, qbase + j);
                    uint4 u = *(const uint4*)&xin[(size_t)s * 128 + ql * 8];
                    f0 += bflo(u.x); f1 += bfhi(u.x); f2 += bflo(u.y); f3 += bfhi(u.y);
                    f4 += bflo(u.z); f5 += bfhi(u.z); f6 += bflo(u.w); f7 += bfhi(u.w);
                }
            }
            ushort o[8] = { f2bf(f0 * inv), f2bf(f1 * inv), f2bf(f2 * inv), f2bf(f3 * inv),
                            f2bf(f4 * inv), f2bf(f5 * inv), f2bf(f6 * inv), f2bf(f7 * inv) };
            *(uint4*)&mlds[ln][ql * 8] = *(const uint4*)o;
        }
    }
    __syncthreads();

    // phase 2: GEMM 32 nodes x 128 channels; wave w owns channels w*32..w*32+31
    const int lrow = lane & 15;
    const int lgrp = lane >> 4;
    f32x4 acc[2][2];                       // [node-tile][ch-tile]
    #pragma unroll
    for (int nt = 0; nt < 2; nt++)
        #pragma unroll
        for (int ct = 0; ct < 2; ct++)
            acc[nt][ct] = (f32x4){0.f, 0.f, 0.f, 0.f};

    #pragma unroll
    for (int ks = 0; ks < KT; ks += 32) {
        const int ac = (ks < K) ? ks : (ks - K);
        const ushort* Xb = (ks < K) ? &mlds[0][0] : &slds[0][0];
        bf16x8 x0 = *(const bf16x8*)&Xb[(lrow) * RP + ac + lgrp * 8];
        bf16x8 x1 = *(const bf16x8*)&Xb[(16 + lrow) * RP + ac + lgrp * 8];
        bf16x8 wA = *(const bf16x8*)&Wcat[(size_t)(w * 32 + lrow) * KT + ks + lgrp * 8];
        bf16x8 wB = *(const bf16x8*)&Wcat[(size_t)(w * 32 + 16 + lrow) * KT + ks + lgrp * 8];
        acc[0][0] = __builtin_amdgcn_mfma_f32_16x16x32_bf16(wA, x0, acc[0][0], 0, 0, 0);
        acc[0][1] = __builtin_amdgcn_mfma_f32_16x16x32_bf16(wB, x0, acc[0][1], 0, 0, 0);
        acc[1][0] = __builtin_amdgcn_mfma_f32_16x16x32_bf16(wA, x1, acc[1][0], 0, 0, 0);
        acc[1][1] = __builtin_amdgcn_mfma_f32_16x16x32_bf16(wB, x1, acc[1][1], 0, 0, 0);
    }

    // epilogue: lane holds channels (w*32 + ct*16 + lgrp*4 .. +3) of node nb+nt*16+lrow
    #pragma unroll
    for (int ct = 0; ct < 2; ct++) {
        const int ch0 = w * 32 + ct * 16 + lgrp * 4;
        float4 b4 = *(const float4*)&bl[ch0];
        #pragma unroll
        for (int nt = 0; nt < 2; nt++) {
            int n = nb + nt * 16 + lrow;
            float v0 = acc[nt][ct][0] + b4.x;
            float v1 = acc[nt][ct][1] + b4.y;
            float v2 = acc[nt][ct][2] + b4.z;
            float v3 = acc[nt][ct][3] + b4.w;
            if (RELU) {
                v0 = fmaxf(v0, 0.f); v1 = fmaxf(v1, 0.f);
                v2 = fmaxf(v2, 0.f); v3 = fmaxf(v3, 0.f);
            }
            if (OUT_BF16) {
                ushort o[4] = { f2bf(v0), f2bf(v1), f2bf(v2), f2bf(v3) };
                *(uint64_t*)&((ushort*)outv)[(size_t)n * 128 + ch0] = *(const uint64_t*)o;
            } else {
                float4 o = make_float4(v0, v1, v2, v3);
                *(float4*)&((float*)outv)[(size_t)n * 128 + ch0] = o;
            }
        }
    }
}

// ---------------- launch ----------------
extern "C" void kernel_launch(void* const* d_in, const int* in_sizes, int n_in,
                              void* d_out, int out_size, void* d_ws, size_t ws_size,
                              hipStream_t stream) {
    const float* x   = (const float*)d_in[0];
    const void*  er  = d_in[1];
    const float* Wl1 = (const float*)d_in[2];
    const float* bl1 = (const float*)d_in[3];
    const float* Wr1 = (const float*)d_in[4];
    const float* Wl2 = (const float*)d_in[5];
    const float* bl2 = (const float*)d_in[6];
    const float* Wr2 = (const float*)d_in[7];
    float* out = (float*)d_out;

    const int N = NN, E = EE;

    // workspace carve-up (512B aligned)
    char* ws = (char*)d_ws;
    size_t off = 0;
    auto carve = [&](size_t bytes) { char* p = ws + off; off += (bytes + 511) & ~(size_t)511; return p; };
    int*      flag      = (int*)     carve(4);
    int*      ccnt      = (int*)     carve((size_t)NBUCK * 4);
    int*      cfill     = (int*)     carve((size_t)NBUCK * 4);
    int*      coff      = (int*)     carve((size_t)(NBUCK + 1) * 4);
    uint32_t* pbuf      = (uint32_t*)carve((size_t)E * 4);
    int*      offsets   = (int*)     carve((size_t)(N + 1) * 4);
    int*      srcs_sort = (int*)     carve((size_t)E * 4);
    ushort*   xb        = (ushort*)  carve((size_t)N * 64 * 2);
    ushort*   hb        = (ushort*)  carve((size_t)N * 128 * 2);
    ushort*   wc1       = (ushort*)  carve((size_t)128 * 128 * 2);
    ushort*   wc2       = (ushort*)  carve((size_t)128 * 256 * 2);
    (void)ws_size;

    hipMemsetAsync(flag, 0, 4, stream);

    prep_kernel<<<2048, 256, 0, stream>>>(x, (const unsigned int*)er,
                                          Wl1, Wr1, Wl2, Wr2,
                                          xb, wc1, wc2, flag, ccnt, cfill);

    // CSR build: two-level partition with block-level reservation
    coarse_hist<<<512, 256, 0, stream>>>(er, flag, ccnt, E);
    coarse_scan<<<1, 256, 0, stream>>>(ccnt, coff, offsets, E);
    coarse_scatter2<<<CSB, 256, 0, stream>>>(er, flag, coff, cfill, pbuf, E);
    fine_bucket<<<NBUCK, 512, 0, stream>>>(pbuf, coff, offsets, srcs_sort, N);

    const int fb = N / 32;                                   // 3125 (N % 32 == 0)

    // layer 1 (fused aggregate + linear, relu, bf16 out)
    sage_fused<64, true, true><<<fb, 256, 0, stream>>>(offsets, srcs_sort, xb, wc1, bl1, hb, N);
    // layer 2 (fused aggregate + linear, f32 out)
    sage_fused<128, false, false><<<fb, 256, 0, stream>>>(offsets, srcs_sort, hb, wc2, bl2, out, N);
}

// Round 13
// 237.666 us; speedup vs baseline: 1.2348x; 1.2348x over previous
//
#include <hip/hip_runtime.h>
#include <hip/hip_bf16.h>
#include <stdint.h>

#define NN 100000
#define EE 1600000
#define NBUCK 196              // ceil(NN/512): buckets of 512 dst nodes
#define CSB 512                // coarse-scatter blocks
#define MAXB 10240             // LDS edge-buffer cap per bucket (avg 8163, sigma~90)

typedef __attribute__((ext_vector_type(4))) float f32x4;
typedef __attribute__((ext_vector_type(8))) short bf16x8;

__device__ inline ushort f2bf(float f) {
    union { float f; uint32_t u; } v; v.f = f;
    uint32_t u = v.u;
    uint32_t r = (u + 0x7fffu + ((u >> 16) & 1u)) >> 16;   // RNE
    return (ushort)r;
}
__device__ inline float bflo(uint32_t u) {
    union { uint32_t u; float f; } v; v.u = u << 16; return v.f;
}
__device__ inline float bfhi(uint32_t u) {
    union { uint32_t u; float f; } v; v.u = u & 0xffff0000u; return v.f;
}

// ---------------- fused prep: detect dtype + bf16 conversions + zero counters ----
__global__ __launch_bounds__(256) void prep_kernel(
    const float* __restrict__ x, const unsigned int* __restrict__ raw,
    const float* __restrict__ Wl1, const float* __restrict__ Wr1,
    const float* __restrict__ Wl2, const float* __restrict__ Wr2,
    ushort* __restrict__ xb, ushort* __restrict__ wc1, ushort* __restrict__ wc2,
    int* __restrict__ flag, int* __restrict__ ccnt, int* __restrict__ cfill)
{
    const int gid = blockIdx.x * 256 + threadIdx.x;
    const int stride = gridDim.x * 256;

    // dtype detect on first 4096 int64 slots
    if (gid < 4096) {
        if (raw[2 * gid + 1] != 0u) atomicOr(flag, 1);
    }
    // zero bucket counters
    if (gid >= 4096 && gid < 4096 + NBUCK) ccnt[gid - 4096] = 0;
    if (gid >= 4096 + NBUCK && gid < 4096 + 2 * NBUCK) cfill[gid - 4096 - NBUCK] = 0;

    // x -> bf16 (one float4 per iter)
    const int n4 = NN * 64 / 4;
    for (int i = gid; i < n4; i += stride) {
        float4 v = *(const float4*)&x[i * 4];
        ushort o[4] = { f2bf(v.x), f2bf(v.y), f2bf(v.z), f2bf(v.w) };
        *(uint64_t*)&xb[i * 4] = *(const uint64_t*)o;
    }
    // Wcat1 (K=64): wc1[o][0..64)=Wl1, [64..128)=Wr1
    for (int i = gid; i < 128 * 128; i += stride) {
        int o = i >> 7, k = i & 127;
        float v = (k < 64) ? Wl1[o * 64 + k] : Wr1[o * 64 + (k - 64)];
        wc1[o * 128 + k] = f2bf(v);
    }
    // Wcat2 (K=128)
    for (int i = gid; i < 128 * 256; i += stride) {
        int o = i >> 8, k = i & 255;
        float v = (k < 128) ? Wl2[o * 128 + k] : Wr2[o * 128 + (k - 128)];
        wc2[o * 256 + k] = f2bf(v);
    }
}

// ---------------- CSR build: two-level partition (block-reserved) ----------------
__global__ __launch_bounds__(256) void coarse_hist(const void* raw, const int* flag,
                                                   int* ccnt, int E) {
    __shared__ int lh[NBUCK];
    for (int i = threadIdx.x; i < NBUCK; i += 256) lh[i] = 0;
    __syncthreads();
    int stride = gridDim.x * 256;
    if (*flag) {
        const int* p = (const int*)raw;
        for (int e = blockIdx.x * 256 + threadIdx.x; e < E; e += stride)
            atomicAdd(&lh[p[E + e] >> 9], 1);
    } else {
        const long long* p = (const long long*)raw;
        for (int e = blockIdx.x * 256 + threadIdx.x; e < E; e += stride)
            atomicAdd(&lh[((int)p[E + e]) >> 9], 1);
    }
    __syncthreads();
    for (int i = threadIdx.x; i < NBUCK; i += 256)
        if (lh[i]) atomicAdd(&ccnt[i], lh[i]);
}

__global__ void coarse_scan(const int* ccnt, int* coff, int* offsets, int E) {
    __shared__ int part[256];
    int t = threadIdx.x;
    int v[4]; int s = 0;
    #pragma unroll
    for (int j = 0; j < 4; j++) {
        int i = t * 4 + j;
        v[j] = (i < NBUCK) ? ccnt[i] : 0;
        s += v[j];
    }
    part[t] = s; __syncthreads();
    for (int off = 1; off < 256; off <<= 1) {
        int add = (t >= off) ? part[t - off] : 0;
        __syncthreads();
        part[t] += add;
        __syncthreads();
    }
    int run = part[t] - s;
    #pragma unroll
    for (int j = 0; j < 4; j++) {
        int i = t * 4 + j;
        if (i <= NBUCK) coff[i] = run;
        run += v[j];
    }
    if (t == 0) offsets[NN] = E;
}

__global__ __launch_bounds__(256) void coarse_scatter2(const void* raw, const int* flag,
                                                       const int* coff, int* cfill,
                                                       uint32_t* pbuf, int E) {
    __shared__ int lh[NBUCK];
    __shared__ int gbase[NBUCK];
    __shared__ int lfill[NBUCK];
    const int t = threadIdx.x;
    for (int i = t; i < NBUCK; i += 256) { lh[i] = 0; lfill[i] = 0; }
    __syncthreads();
    const int chunk = (E + (int)gridDim.x - 1) / (int)gridDim.x;
    const int s0 = blockIdx.x * chunk;
    const int s1 = min(E, s0 + chunk);
    const bool is32 = (*flag != 0);
    if (is32) {
        const int* p = (const int*)raw;
        for (int e = s0 + t; e < s1; e += 256) atomicAdd(&lh[p[E + e] >> 9], 1);
    } else {
        const long long* p = (const long long*)raw;
        for (int e = s0 + t; e < s1; e += 256) atomicAdd(&lh[((int)p[E + e]) >> 9], 1);
    }
    __syncthreads();
    for (int i = t; i < NBUCK; i += 256)
        gbase[i] = coff[i] + (lh[i] ? atomicAdd(&cfill[i], lh[i]) : 0);
    __syncthreads();
    if (is32) {
        const int* p = (const int*)raw;
        for (int e = s0 + t; e < s1; e += 256) {
            int sr = p[e], d = p[E + e];
            int b = d >> 9;
            int r = atomicAdd(&lfill[b], 1);
            pbuf[gbase[b] + r] = ((uint32_t)(d & 511) << 17) | (uint32_t)sr;
        }
    } else {
        const long long* p = (const long long*)raw;
        for (int e = s0 + t; e < s1; e += 256) {
            int sr = (int)p[e], d = (int)p[E + e];
            int b = d >> 9;
            int r = atomicAdd(&lfill[b], 1);
            pbuf[gbase[b] + r] = ((uint32_t)(d & 511) << 17) | (uint32_t)sr;
        }
    }
}

// Pass D: per 512-node bucket. Scatter packed entries INTO LDS grouped by node,
// insertion-sort each node's segment by src in LDS (gather-locality win), then
// coalesced copy-out. Overflow beyond MAXB spills to global unsorted (mean is
// order-insensitive; only locality is lost for the tail).
__global__ __launch_bounds__(512) void fine_bucket(const uint32_t* __restrict__ pbuf,
                                                   const int* __restrict__ coff,
                                                   int* __restrict__ offsets,
                                                   int* __restrict__ srcs_sort, int N) {
    __shared__ int cnt[512], sc[512], fil[512];
    __shared__ uint32_t sbuf[MAXB];
    const int b = blockIdx.x, t = threadIdx.x;
    const int s = coff[b], e = coff[b + 1];
    cnt[t] = 0; fil[t] = 0;
    __syncthreads();
    for (int i = s + t; i < e; i += 512) atomicAdd(&cnt[pbuf[i] >> 17], 1);
    __syncthreads();
    sc[t] = cnt[t];
    __syncthreads();
    for (int off = 1; off < 512; off <<= 1) {
        int add = (t >= off) ? sc[t - off] : 0;
        __syncthreads();
        sc[t] += add;
        __syncthreads();
    }
    const int nb0 = b * 512;
    if (nb0 + t < N) offsets[nb0 + t] = s + sc[t] - cnt[t];
    // scatter into LDS at final (node-grouped) positions
    for (int i = s + t; i < e; i += 512) {
        uint32_t p = pbuf[i];
        int dl = (int)(p >> 17);
        int pos = (sc[dl] - cnt[dl]) + atomicAdd(&fil[dl], 1);
        if (pos < MAXB) sbuf[pos] = p;
        else srcs_sort[s + pos] = (int)(p & 0x1FFFFu);   // overflow: unsorted
    }
    __syncthreads();
    // per-node insertion sort (packed value order == src order within a node)
    {
        int a  = sc[t] - cnt[t];
        int e2 = min(a + cnt[t], MAXB);
        for (int i = a + 1; i < e2; i++) {
            uint32_t v = sbuf[i];
            int j = i - 1;
            while (j >= a && sbuf[j] > v) { sbuf[j + 1] = sbuf[j]; j--; }
            sbuf[j + 1] = v;
        }
    }
    __syncthreads();
    // coalesced copy-out
    const int tot = min(e - s, MAXB);
    for (int i = t; i < tot; i += 512)
        srcs_sort[s + i] = (int)(sbuf[i] & 0x1FFFFu);
}

// ---------------- FUSED aggregate + SAGE linear ----------------
// Block = 4 waves = 32 nodes (N % 32 == 0).
// Phase 1 (node-per-quarter-wave): each 16-lane quarter owns one node's edge
//   stream (src-sorted); lane covers K/16 channels, one 16B/8B load per edge.
// Phase 2: 32x128 GEMM from LDS (swapped-operand MFMA, contiguous stores).
template<int K, bool RELU, bool OUT_BF16>
__global__ __launch_bounds__(256) void sage_fused(
    const int* __restrict__ offsets, const int* __restrict__ srcs,
    const ushort* __restrict__ xin, const ushort* __restrict__ Wcat,
    const float* __restrict__ bl, void* __restrict__ outv, int N)
{
    constexpr int KT = 2 * K;
    constexpr int RP = K + 8;                 // padded row (ushorts)
    __shared__ ushort mlds[32][RP];
    __shared__ ushort slds[32][RP];
    const int t = threadIdx.x;
    const int w = t >> 6;
    const int lane = t & 63;
    const int nb = blockIdx.x * 32;

    // stage self rows (coalesced 16B chunks)
    #pragma unroll
    for (int idx = t; idx < 32 * (K / 8); idx += 256) {
        int r = idx / (K / 8), c = idx % (K / 8);
        *(uint4*)&slds[r][c * 8] = *(const uint4*)&xin[(size_t)(nb + r) * K + c * 8];
    }

    const int q     = lane >> 4;              // quarter 0-3
    const int ql    = lane & 15;
    const int qbase = lane & 48;              // shfl base of own quarter

    // batch-load the 9 offsets this wave needs
    int offv = 0;
    if (lane < 9) offv = offsets[nb + w * 8 + lane];

    // phase 1: 2 passes x 4 quarters = 8 nodes per wave
    for (int pi = 0; pi < 2; pi++) {
        const int ln = w * 8 + pi * 4 + q;            // local node index
        const int s0 = __shfl(offv, pi * 4 + q);
        const int s1 = __shfl(offv, pi * 4 + q + 1);
        const float inv = 1.0f / fmaxf((float)(s1 - s0), 1.0f);

        if (K == 64) {
            float f0=0.f, f1=0.f, f2=0.f, f3=0.f;
            for (int base = s0; base < s1; base += 16) {
                int cnt = min(16, s1 - base);
                int myidx = (base + ql < s1) ? srcs[base + ql] : 0;
                int j = 0;
                for (; j + 4 <= cnt; j += 4) {
                    int sA = __shfl(myidx, qbase + j);
                    int sB = __shfl(myidx, qbase + j + 1);
                    int sC = __shfl(myidx, qbase + j + 2);
                    int sD = __shfl(myidx, qbase + j + 3);
                    uint2 uA = *(const uint2*)&xin[(size_t)sA * 64 + ql * 4];
                    uint2 uB = *(const uint2*)&xin[(size_t)sB * 64 + ql * 4];
                    uint2 uC = *(const uint2*)&xin[(size_t)sC * 64 + ql * 4];
                    uint2 uD = *(const uint2*)&xin[(size_t)sD * 64 + ql * 4];
                    f0 += bflo(uA.x); f1 += bfhi(uA.x); f2 += bflo(uA.y); f3 += bfhi(uA.y);
                    f0 += bflo(uB.x); f1 += bfhi(uB.x); f2 += bflo(uB.y); f3 += bfhi(uB.y);
                    f0 += bflo(uC.x); f1 += bfhi(uC.x); f2 += bflo(uC.y); f3 += bfhi(uC.y);
                    f0 += bflo(uD.x); f1 += bfhi(uD.x); f2 += bflo(uD.y); f3 += bfhi(uD.y);
                }
                for (; j < cnt; j++) {
                    int s = __shfl(myidx, qbase + j);
                    uint2 u = *(const uint2*)&xin[(size_t)s * 64 + ql * 4];
                    f0 += bflo(u.x); f1 += bfhi(u.x); f2 += bflo(u.y); f3 += bfhi(u.y);
                }
            }
            ushort o[4] = { f2bf(f0 * inv), f2bf(f1 * inv), f2bf(f2 * inv), f2bf(f3 * inv) };
            *(uint64_t*)&mlds[ln][ql * 4] = *(const uint64_t*)o;
        } else {
            float f0=0.f, f1=0.f, f2=0.f, f3=0.f, f4=0.f, f5=0.f, f6=0.f, f7=0.f;
            for (int base = s0; base < s1; base += 16) {
                int cnt = min(16, s1 - base);
                int myidx = (base + ql < s1) ? srcs[base + ql] : 0;
                int j = 0;
                for (; j + 4 <= cnt; j += 4) {
                    int sA = __shfl(myidx, qbase + j);
                    int sB = __shfl(myidx, qbase + j + 1);
                    int sC = __shfl(myidx, qbase + j + 2);
                    int sD = __shfl(myidx, qbase + j + 3);
                    uint4 uA = *(const uint4*)&xin[(size_t)sA * 128 + ql * 8];
                    uint4 uB = *(const uint4*)&xin[(size_t)sB * 128 + ql * 8];
                    uint4 uC = *(const uint4*)&xin[(size_t)sC * 128 + ql * 8];
                    uint4 uD = *(const uint4*)&xin[(size_t)sD * 128 + ql * 8];
                    f0 += bflo(uA.x); f1 += bfhi(uA.x); f2 += bflo(uA.y); f3 += bfhi(uA.y);
                    f4 += bflo(uA.z); f5 += bfhi(uA.z); f6 += bflo(uA.w); f7 += bfhi(uA.w);
                    f0 += bflo(uB.x); f1 += bfhi(uB.x); f2 += bflo(uB.y); f3 += bfhi(uB.y);
                    f4 += bflo(uB.z); f5 += bfhi(uB.z); f6 += bflo(uB.w); f7 += bfhi(uB.w);
                    f0 += bflo(uC.x); f1 += bfhi(uC.x); f2 += bflo(uC.y); f3 += bfhi(uC.y);
                    f4 += bflo(uC.z); f5 += bfhi(uC.z); f6 += bflo(uC.w); f7 += bfhi(uC.w);
                    f0 += bflo(uD.x); f1 += bfhi(uD.x); f2 += bflo(uD.y); f3 += bfhi(uD.y);
                    f4 += bflo(uD.z); f5 += bfhi(uD.z); f6 += bflo(uD.w); f7 += bfhi(uD.w);
                }
                for (; j < cnt; j++) {
                    int s = __shfl(myidx, qbase + j);
                    uint4 u = *(const uint4*)&xin[(size_t)s * 128 + ql * 8];
                    f0 += bflo(u.x); f1 += bfhi(u.x); f2 += bflo(u.y); f3 += bfhi(u.y);
                    f4 += bflo(u.z); f5 += bfhi(u.z); f6 += bflo(u.w); f7 += bfhi(u.w);
                }
            }
            ushort o[8] = { f2bf(f0 * inv), f2bf(f1 * inv), f2bf(f2 * inv), f2bf(f3 * inv),
                            f2bf(f4 * inv), f2bf(f5 * inv), f2bf(f6 * inv), f2bf(f7 * inv) };
            *(uint4*)&mlds[ln][ql * 8] = *(const uint4*)o;
        }
    }
    __syncthreads();

    // phase 2: GEMM 32 nodes x 128 channels; wave w owns channels w*32..w*32+31
    const int lrow = lane & 15;
    const int lgrp = lane >> 4;
    f32x4 acc[2][2];                       // [node-tile][ch-tile]
    #pragma unroll
    for (int nt = 0; nt < 2; nt++)
        #pragma unroll
        for (int ct = 0; ct < 2; ct++)
            acc[nt][ct] = (f32x4){0.f, 0.f, 0.f, 0.f};

    #pragma unroll
    for (int ks = 0; ks < KT; ks += 32) {
        const int ac = (ks < K) ? ks : (ks - K);
        const ushort* Xb = (ks < K) ? &mlds[0][0] : &slds[0][0];
        bf16x8 x0 = *(const bf16x8*)&Xb[(lrow) * RP + ac + lgrp * 8];
        bf16x8 x1 = *(const bf16x8*)&Xb[(16 + lrow) * RP + ac + lgrp * 8];
        bf16x8 wA = *(const bf16x8*)&Wcat[(size_t)(w * 32 + lrow) * KT + ks + lgrp * 8];
        bf16x8 wB = *(const bf16x8*)&Wcat[(size_t)(w * 32 + 16 + lrow) * KT + ks + lgrp * 8];
        acc[0][0] = __builtin_amdgcn_mfma_f32_16x16x32_bf16(wA, x0, acc[0][0], 0, 0, 0);
        acc[0][1] = __builtin_amdgcn_mfma_f32_16x16x32_bf16(wB, x0, acc[0][1], 0, 0, 0);
        acc[1][0] = __builtin_amdgcn_mfma_f32_16x16x32_bf16(wA, x1, acc[1][0], 0, 0, 0);
        acc[1][1] = __builtin_amdgcn_mfma_f32_16x16x32_bf16(wB, x1, acc[1][1], 0, 0, 0);
    }

    // epilogue: lane holds channels (w*32 + ct*16 + lgrp*4 .. +3) of node nb+nt*16+lrow
    #pragma unroll
    for (int ct = 0; ct < 2; ct++) {
        const int ch0 = w * 32 + ct * 16 + lgrp * 4;
        float4 b4 = *(const float4*)&bl[ch0];
        #pragma unroll
        for (int nt = 0; nt < 2; nt++) {
            int n = nb + nt * 16 + lrow;
            float v0 = acc[nt][ct][0] + b4.x;
            float v1 = acc[nt][ct][1] + b4.y;
            float v2 = acc[nt][ct][2] + b4.z;
            float v3 = acc[nt][ct][3] + b4.w;
            if (RELU) {
                v0 = fmaxf(v0, 0.f); v1 = fmaxf(v1, 0.f);
                v2 = fmaxf(v2, 0.f); v3 = fmaxf(v3, 0.f);
            }
            if (OUT_BF16) {
                ushort o[4] = { f2bf(v0), f2bf(v1), f2bf(v2), f2bf(v3) };
                *(uint64_t*)&((ushort*)outv)[(size_t)n * 128 + ch0] = *(const uint64_t*)o;
            } else {
                float4 o = make_float4(v0, v1, v2, v3);
                *(float4*)&((float*)outv)[(size_t)n * 128 + ch0] = o;
            }
        }
    }
}

// ---------------- launch ----------------
extern "C" void kernel_launch(void* const* d_in, const int* in_sizes, int n_in,
                              void* d_out, int out_size, void* d_ws, size_t ws_size,
                              hipStream_t stream) {
    const float* x   = (const float*)d_in[0];
    const void*  er  = d_in[1];
    const float* Wl1 = (const float*)d_in[2];
    const float* bl1 = (const float*)d_in[3];
    const float* Wr1 = (const float*)d_in[4];
    const float* Wl2 = (const float*)d_in[5];
    const float* bl2 = (const float*)d_in[6];
    const float* Wr2 = (const float*)d_in[7];
    float* out = (float*)d_out;

    const int N = NN, E = EE;

    // workspace carve-up (512B aligned)
    char* ws = (char*)d_ws;
    size_t off = 0;
    auto carve = [&](size_t bytes) { char* p = ws + off; off += (bytes + 511) & ~(size_t)511; return p; };
    int*      flag      = (int*)     carve(4);
    int*      ccnt      = (int*)     carve((size_t)NBUCK * 4);
    int*      cfill     = (int*)     carve((size_t)NBUCK * 4);
    int*      coff      = (int*)     carve((size_t)(NBUCK + 1) * 4);
    uint32_t* pbuf      = (uint32_t*)carve((size_t)E * 4);
    int*      offsets   = (int*)     carve((size_t)(N + 1) * 4);
    int*      srcs_sort = (int*)     carve((size_t)E * 4);
    ushort*   xb        = (ushort*)  carve((size_t)N * 64 * 2);
    ushort*   hb        = (ushort*)  carve((size_t)N * 128 * 2);
    ushort*   wc1       = (ushort*)  carve((size_t)128 * 128 * 2);
    ushort*   wc2       = (ushort*)  carve((size_t)128 * 256 * 2);
    (void)ws_size;

    hipMemsetAsync(flag, 0, 4, stream);

    prep_kernel<<<2048, 256, 0, stream>>>(x, (const unsigned int*)er,
                                          Wl1, Wr1, Wl2, Wr2,
                                          xb, wc1, wc2, flag, ccnt, cfill);

    // CSR build: two-level partition with block-level reservation
    coarse_hist<<<512, 256, 0, stream>>>(er, flag, ccnt, E);
    coarse_scan<<<1, 256, 0, stream>>>(ccnt, coff, offsets, E);
    coarse_scatter2<<<CSB, 256, 0, stream>>>(er, flag, coff, cfill, pbuf, E);
    fine_bucket<<<NBUCK, 512, 0, stream>>>(pbuf, coff, offsets, srcs_sort, N);

    const int fb = N / 32;                                   // 3125 (N % 32 == 0)

    // layer 1 (fused aggregate + linear, relu, bf16 out)
    sage_fused<64, true, true><<<fb, 256, 0, stream>>>(offsets, srcs_sort, xb, wc1, bl1, hb, N);
    // layer 2 (fused aggregate + linear, f32 out)
    sage_fused<128, false, false><<<fb, 256, 0, stream>>>(offsets, srcs_sort, hb, wc2, bl2, out, N);
}

// Round 14
// 205.661 us; speedup vs baseline: 1.4269x; 1.1556x over previous
//
#include <hip/hip_runtime.h>
#include <hip/hip_bf16.h>
#include <stdint.h>

#define NN 100000
#define EE 1600000
#define NBUCK 196              // ceil(NN/512): buckets of 512 dst nodes
#define CSB 512                // coarse-scatter blocks

typedef __attribute__((ext_vector_type(4))) float f32x4;
typedef __attribute__((ext_vector_type(8))) short bf16x8;

__device__ inline ushort f2bf(float f) {
    union { float f; uint32_t u; } v; v.f = f;
    uint32_t u = v.u;
    uint32_t r = (u + 0x7fffu + ((u >> 16) & 1u)) >> 16;   // RNE
    return (ushort)r;
}
__device__ inline float bflo(uint32_t u) {
    union { uint32_t u; float f; } v; v.u = u << 16; return v.f;
}
__device__ inline float bfhi(uint32_t u) {
    union { uint32_t u; float f; } v; v.u = u & 0xffff0000u; return v.f;
}

// ---------------- fused prep: detect dtype + bf16 conversions + zero counters ----
__global__ __launch_bounds__(256) void prep_kernel(
    const float* __restrict__ x, const unsigned int* __restrict__ raw,
    const float* __restrict__ Wl1, const float* __restrict__ Wr1,
    const float* __restrict__ Wl2, const float* __restrict__ Wr2,
    ushort* __restrict__ xb, ushort* __restrict__ wc1, ushort* __restrict__ wc2,
    int* __restrict__ flag, int* __restrict__ ccnt, int* __restrict__ cfill)
{
    const int gid = blockIdx.x * 256 + threadIdx.x;
    const int stride = gridDim.x * 256;

    if (gid < 4096) {
        if (raw[2 * gid + 1] != 0u) atomicOr(flag, 1);
    }
    if (gid >= 4096 && gid < 4096 + NBUCK) ccnt[gid - 4096] = 0;
    if (gid >= 4096 + NBUCK && gid < 4096 + 2 * NBUCK) cfill[gid - 4096 - NBUCK] = 0;

    const int n4 = NN * 64 / 4;
    for (int i = gid; i < n4; i += stride) {
        float4 v = *(const float4*)&x[i * 4];
        ushort o[4] = { f2bf(v.x), f2bf(v.y), f2bf(v.z), f2bf(v.w) };
        *(uint64_t*)&xb[i * 4] = *(const uint64_t*)o;
    }
    for (int i = gid; i < 128 * 128; i += stride) {
        int o = i >> 7, k = i & 127;
        float v = (k < 64) ? Wl1[o * 64 + k] : Wr1[o * 64 + (k - 64)];
        wc1[o * 128 + k] = f2bf(v);
    }
    for (int i = gid; i < 128 * 256; i += stride) {
        int o = i >> 8, k = i & 255;
        float v = (k < 128) ? Wl2[o * 128 + k] : Wr2[o * 128 + (k - 128)];
        wc2[o * 256 + k] = f2bf(v);
    }
}

// ---------------- CSR build: two-level partition (block-reserved) ----------------
__global__ __launch_bounds__(256) void coarse_hist(const void* raw, const int* flag,
                                                   int* ccnt, int E) {
    __shared__ int lh[NBUCK];
    for (int i = threadIdx.x; i < NBUCK; i += 256) lh[i] = 0;
    __syncthreads();
    int stride = gridDim.x * 256;
    if (*flag) {
        const int* p = (const int*)raw;
        for (int e = blockIdx.x * 256 + threadIdx.x; e < E; e += stride)
            atomicAdd(&lh[p[E + e] >> 9], 1);
    } else {
        const long long* p = (const long long*)raw;
        for (int e = blockIdx.x * 256 + threadIdx.x; e < E; e += stride)
            atomicAdd(&lh[((int)p[E + e]) >> 9], 1);
    }
    __syncthreads();
    for (int i = threadIdx.x; i < NBUCK; i += 256)
        if (lh[i]) atomicAdd(&ccnt[i], lh[i]);
}

__global__ void coarse_scan(const int* ccnt, int* coff, int* offsets, int E) {
    __shared__ int part[256];
    int t = threadIdx.x;
    int v[4]; int s = 0;
    #pragma unroll
    for (int j = 0; j < 4; j++) {
        int i = t * 4 + j;
        v[j] = (i < NBUCK) ? ccnt[i] : 0;
        s += v[j];
    }
    part[t] = s; __syncthreads();
    for (int off = 1; off < 256; off <<= 1) {
        int add = (t >= off) ? part[t - off] : 0;
        __syncthreads();
        part[t] += add;
        __syncthreads();
    }
    int run = part[t] - s;
    #pragma unroll
    for (int j = 0; j < 4; j++) {
        int i = t * 4 + j;
        if (i <= NBUCK) coff[i] = run;
        run += v[j];
    }
    if (t == 0) offsets[NN] = E;
}

__global__ __launch_bounds__(256) void coarse_scatter2(const void* raw, const int* flag,
                                                       const int* coff, int* cfill,
                                                       uint32_t* pbuf, int E) {
    __shared__ int lh[NBUCK];
    __shared__ int gbase[NBUCK];
    __shared__ int lfill[NBUCK];
    const int t = threadIdx.x;
    for (int i = t; i < NBUCK; i += 256) { lh[i] = 0; lfill[i] = 0; }
    __syncthreads();
    const int chunk = (E + (int)gridDim.x - 1) / (int)gridDim.x;
    const int s0 = blockIdx.x * chunk;
    const int s1 = min(E, s0 + chunk);
    const bool is32 = (*flag != 0);
    if (is32) {
        const int* p = (const int*)raw;
        for (int e = s0 + t; e < s1; e += 256) atomicAdd(&lh[p[E + e] >> 9], 1);
    } else {
        const long long* p = (const long long*)raw;
        for (int e = s0 + t; e < s1; e += 256) atomicAdd(&lh[((int)p[E + e]) >> 9], 1);
    }
    __syncthreads();
    for (int i = t; i < NBUCK; i += 256)
        gbase[i] = coff[i] + (lh[i] ? atomicAdd(&cfill[i], lh[i]) : 0);
    __syncthreads();
    if (is32) {
        const int* p = (const int*)raw;
        for (int e = s0 + t; e < s1; e += 256) {
            int sr = p[e], d = p[E + e];
            int b = d >> 9;
            int r = atomicAdd(&lfill[b], 1);
            pbuf[gbase[b] + r] = ((uint32_t)(d & 511) << 17) | (uint32_t)sr;
        }
    } else {
        const long long* p = (const long long*)raw;
        for (int e = s0 + t; e < s1; e += 256) {
            int sr = (int)p[e], d = (int)p[E + e];
            int b = d >> 9;
            int r = atomicAdd(&lfill[b], 1);
            pbuf[gbase[b] + r] = ((uint32_t)(d & 511) << 17) | (uint32_t)sr;
        }
    }
}

// Pass D: per 512-node bucket: LDS hist + scan -> offsets; scatter srcs within
// the bucket's contiguous ~32KB window (L2-resident). NO sort — measured null.
__global__ __launch_bounds__(512) void fine_bucket(const uint32_t* __restrict__ pbuf,
                                                   const int* __restrict__ coff,
                                                   int* __restrict__ offsets,
                                                   int* __restrict__ srcs_sort, int N) {
    __shared__ int cnt[512], sc[512], fil[512];
    const int b = blockIdx.x, t = threadIdx.x;
    const int s = coff[b], e = coff[b + 1];
    cnt[t] = 0; fil[t] = 0;
    __syncthreads();
    for (int i = s + t; i < e; i += 512) atomicAdd(&cnt[pbuf[i] >> 17], 1);
    __syncthreads();
    sc[t] = cnt[t];
    __syncthreads();
    for (int off = 1; off < 512; off <<= 1) {
        int add = (t >= off) ? sc[t - off] : 0;
        __syncthreads();
        sc[t] += add;
        __syncthreads();
    }
    const int nb0 = b * 512;
    if (nb0 + t < N) offsets[nb0 + t] = s + sc[t] - cnt[t];
    for (int i = s + t; i < e; i += 512) {
        uint32_t p = pbuf[i];
        int dl = (int)(p >> 17);
        int sr = (int)(p & 0x1FFFFu);
        int pos = s + (sc[dl] - cnt[dl]) + atomicAdd(&fil[dl], 1);
        srcs_sort[pos] = sr;
    }
}

// ---------------- FUSED aggregate + SAGE linear ----------------
// Block = 4 waves = 32 nodes (N % 32 == 0). LDS minimized (mean tile only,
// 8.7KB) -> 8 blocks/CU for max outstanding-gather concurrency.
// Phase 1 (node-per-quarter-wave): each 16-lane quarter owns one node's edge
//   stream; lane covers K/16 channels, one 16B/8B load per edge.
// Phase 2: 32x128 GEMM; mean fragments from LDS, SELF fragments straight from
//   global (coalesced, L2-hot, latency hidden under MFMA).
template<int K, bool RELU, bool OUT_BF16>
__global__ __launch_bounds__(256, 8) void sage_fused(
    const int* __restrict__ offsets, const int* __restrict__ srcs,
    const ushort* __restrict__ xin, const ushort* __restrict__ Wcat,
    const float* __restrict__ bl, void* __restrict__ outv, int N)
{
    constexpr int KT = 2 * K;
    constexpr int RP = K + 8;                 // padded row (ushorts)
    __shared__ ushort mlds[32][RP];
    const int t = threadIdx.x;
    const int w = t >> 6;
    const int lane = t & 63;
    const int nb = blockIdx.x * 32;

    const int q     = lane >> 4;              // quarter 0-3
    const int ql    = lane & 15;
    const int qbase = lane & 48;              // shfl base of own quarter

    // batch-load the 9 offsets this wave needs
    int offv = 0;
    if (lane < 9) offv = offsets[nb + w * 8 + lane];

    // phase 1: 2 passes x 4 quarters = 8 nodes per wave
    for (int pi = 0; pi < 2; pi++) {
        const int ln = w * 8 + pi * 4 + q;            // local node index
        const int s0 = __shfl(offv, pi * 4 + q);
        const int s1 = __shfl(offv, pi * 4 + q + 1);
        const float inv = 1.0f / fmaxf((float)(s1 - s0), 1.0f);

        if (K == 64) {
            float f0=0.f, f1=0.f, f2=0.f, f3=0.f;
            for (int base = s0; base < s1; base += 16) {
                int cnt = min(16, s1 - base);
                int myidx = (base + ql < s1) ? srcs[base + ql] : 0;
                int j = 0;
                for (; j + 4 <= cnt; j += 4) {
                    int sA = __shfl(myidx, qbase + j);
                    int sB = __shfl(myidx, qbase + j + 1);
                    int sC = __shfl(myidx, qbase + j + 2);
                    int sD = __shfl(myidx, qbase + j + 3);
                    uint2 uA = *(const uint2*)&xin[(size_t)sA * 64 + ql * 4];
                    uint2 uB = *(const uint2*)&xin[(size_t)sB * 64 + ql * 4];
                    uint2 uC = *(const uint2*)&xin[(size_t)sC * 64 + ql * 4];
                    uint2 uD = *(const uint2*)&xin[(size_t)sD * 64 + ql * 4];
                    f0 += bflo(uA.x); f1 += bfhi(uA.x); f2 += bflo(uA.y); f3 += bfhi(uA.y);
                    f0 += bflo(uB.x); f1 += bfhi(uB.x); f2 += bflo(uB.y); f3 += bfhi(uB.y);
                    f0 += bflo(uC.x); f1 += bfhi(uC.x); f2 += bflo(uC.y); f3 += bfhi(uC.y);
                    f0 += bflo(uD.x); f1 += bfhi(uD.x); f2 += bflo(uD.y); f3 += bfhi(uD.y);
                }
                for (; j < cnt; j++) {
                    int s = __shfl(myidx, qbase + j);
                    uint2 u = *(const uint2*)&xin[(size_t)s * 64 + ql * 4];
                    f0 += bflo(u.x); f1 += bfhi(u.x); f2 += bflo(u.y); f3 += bfhi(u.y);
                }
            }
            ushort o[4] = { f2bf(f0 * inv), f2bf(f1 * inv), f2bf(f2 * inv), f2bf(f3 * inv) };
            *(uint64_t*)&mlds[ln][ql * 4] = *(const uint64_t*)o;
        } else {
            float f0=0.f, f1=0.f, f2=0.f, f3=0.f, f4=0.f, f5=0.f, f6=0.f, f7=0.f;
            for (int base = s0; base < s1; base += 16) {
                int cnt = min(16, s1 - base);
                int myidx = (base + ql < s1) ? srcs[base + ql] : 0;
                int j = 0;
                for (; j + 4 <= cnt; j += 4) {
                    int sA = __shfl(myidx, qbase + j);
                    int sB = __shfl(myidx, qbase + j + 1);
                    int sC = __shfl(myidx, qbase + j + 2);
                    int sD = __shfl(myidx, qbase + j + 3);
                    uint4 uA = *(const uint4*)&xin[(size_t)sA * 128 + ql * 8];
                    uint4 uB = *(const uint4*)&xin[(size_t)sB * 128 + ql * 8];
                    uint4 uC = *(const uint4*)&xin[(size_t)sC * 128 + ql * 8];
                    uint4 uD = *(const uint4*)&xin[(size_t)sD * 128 + ql * 8];
                    f0 += bflo(uA.x); f1 += bfhi(uA.x); f2 += bflo(uA.y); f3 += bfhi(uA.y);
                    f4 += bflo(uA.z); f5 += bfhi(uA.z); f6 += bflo(uA.w); f7 += bfhi(uA.w);
                    f0 += bflo(uB.x); f1 += bfhi(uB.x); f2 += bflo(uB.y); f3 += bfhi(uB.y);
                    f4 += bflo(uB.z); f5 += bfhi(uB.z); f6 += bflo(uB.w); f7 += bfhi(uB.w);
                    f0 += bflo(uC.x); f1 += bfhi(uC.x); f2 += bflo(uC.y); f3 += bfhi(uC.y);
                    f4 += bflo(uC.z); f5 += bfhi(uC.z); f6 += bflo(uC.w); f7 += bfhi(uC.w);
                    f0 += bflo(uD.x); f1 += bfhi(uD.x); f2 += bflo(uD.y); f3 += bfhi(uD.y);
                    f4 += bflo(uD.z); f5 += bfhi(uD.z); f6 += bflo(uD.w); f7 += bfhi(uD.w);
                }
                for (; j < cnt; j++) {
                    int s = __shfl(myidx, qbase + j);
                    uint4 u = *(const uint4*)&xin[(size_t)s * 128 + ql * 8];
                    f0 += bflo(u.x); f1 += bfhi(u.x); f2 += bflo(u.y); f3 += bfhi(u.y);
                    f4 += bflo(u.z); f5 += bfhi(u.z); f6 += bflo(u.w); f7 += bfhi(u.w);
                }
            }
            ushort o[8] = { f2bf(f0 * inv), f2bf(f1 * inv), f2bf(f2 * inv), f2bf(f3 * inv),
                            f2bf(f4 * inv), f2bf(f5 * inv), f2bf(f6 * inv), f2bf(f7 * inv) };
            *(uint4*)&mlds[ln][ql * 8] = *(const uint4*)o;
        }
    }
    __syncthreads();

    // phase 2: GEMM 32 nodes x 128 channels; wave w owns channels w*32..w*32+31
    const int lrow = lane & 15;
    const int lgrp = lane >> 4;
    f32x4 acc[2][2];                       // [node-tile][ch-tile]
    #pragma unroll
    for (int nt = 0; nt < 2; nt++)
        #pragma unroll
        for (int ct = 0; ct < 2; ct++)
            acc[nt][ct] = (f32x4){0.f, 0.f, 0.f, 0.f};

    #pragma unroll
    for (int ks = 0; ks < KT; ks += 32) {
        bf16x8 x0, x1;
        if (ks < K) {                         // mean tile from LDS
            x0 = *(const bf16x8*)&mlds[lrow][ks + lgrp * 8];
            x1 = *(const bf16x8*)&mlds[16 + lrow][ks + lgrp * 8];
        } else {                              // self rows straight from global
            const int ac = ks - K;
            x0 = *(const bf16x8*)&xin[(size_t)(nb + lrow) * K + ac + lgrp * 8];
            x1 = *(const bf16x8*)&xin[(size_t)(nb + 16 + lrow) * K + ac + lgrp * 8];
        }
        bf16x8 wA = *(const bf16x8*)&Wcat[(size_t)(w * 32 + lrow) * KT + ks + lgrp * 8];
        bf16x8 wB = *(const bf16x8*)&Wcat[(size_t)(w * 32 + 16 + lrow) * KT + ks + lgrp * 8];
        acc[0][0] = __builtin_amdgcn_mfma_f32_16x16x32_bf16(wA, x0, acc[0][0], 0, 0, 0);
        acc[0][1] = __builtin_amdgcn_mfma_f32_16x16x32_bf16(wB, x0, acc[0][1], 0, 0, 0);
        acc[1][0] = __builtin_amdgcn_mfma_f32_16x16x32_bf16(wA, x1, acc[1][0], 0, 0, 0);
        acc[1][1] = __builtin_amdgcn_mfma_f32_16x16x32_bf16(wB, x1, acc[1][1], 0, 0, 0);
    }

    // epilogue: lane holds channels (w*32 + ct*16 + lgrp*4 .. +3) of node nb+nt*16+lrow
    #pragma unroll
    for (int ct = 0; ct < 2; ct++) {
        const int ch0 = w * 32 + ct * 16 + lgrp * 4;
        float4 b4 = *(const float4*)&bl[ch0];
        #pragma unroll
        for (int nt = 0; nt < 2; nt++) {
            int n = nb + nt * 16 + lrow;
            float v0 = acc[nt][ct][0] + b4.x;
            float v1 = acc[nt][ct][1] + b4.y;
            float v2 = acc[nt][ct][2] + b4.z;
            float v3 = acc[nt][ct][3] + b4.w;
            if (RELU) {
                v0 = fmaxf(v0, 0.f); v1 = fmaxf(v1, 0.f);
                v2 = fmaxf(v2, 0.f); v3 = fmaxf(v3, 0.f);
            }
            if (OUT_BF16) {
                ushort o[4] = { f2bf(v0), f2bf(v1), f2bf(v2), f2bf(v3) };
                *(uint64_t*)&((ushort*)outv)[(size_t)n * 128 + ch0] = *(const uint64_t*)o;
            } else {
                float4 o = make_float4(v0, v1, v2, v3);
                *(float4*)&((float*)outv)[(size_t)n * 128 + ch0] = o;
            }
        }
    }
}

// ---------------- launch ----------------
extern "C" void kernel_launch(void* const* d_in, const int* in_sizes, int n_in,
                              void* d_out, int out_size, void* d_ws, size_t ws_size,
                              hipStream_t stream) {
    const float* x   = (const float*)d_in[0];
    const void*  er  = d_in[1];
    const float* Wl1 = (const float*)d_in[2];
    const float* bl1 = (const float*)d_in[3];
    const float* Wr1 = (const float*)d_in[4];
    const float* Wl2 = (const float*)d_in[5];
    const float* bl2 = (const float*)d_in[6];
    const float* Wr2 = (const float*)d_in[7];
    float* out = (float*)d_out;

    const int N = NN, E = EE;

    // workspace carve-up (512B aligned)
    char* ws = (char*)d_ws;
    size_t off = 0;
    auto carve = [&](size_t bytes) { char* p = ws + off; off += (bytes + 511) & ~(size_t)511; return p; };
    int*      flag      = (int*)     carve(4);
    int*      ccnt      = (int*)     carve((size_t)NBUCK * 4);
    int*      cfill     = (int*)     carve((size_t)NBUCK * 4);
    int*      coff      = (int*)     carve((size_t)(NBUCK + 1) * 4);
    uint32_t* pbuf      = (uint32_t*)carve((size_t)E * 4);
    int*      offsets   = (int*)     carve((size_t)(N + 1) * 4);
    int*      srcs_sort = (int*)     carve((size_t)E * 4);
    ushort*   xb        = (ushort*)  carve((size_t)N * 64 * 2);
    ushort*   hb        = (ushort*)  carve((size_t)N * 128 * 2);
    ushort*   wc1       = (ushort*)  carve((size_t)128 * 128 * 2);
    ushort*   wc2       = (ushort*)  carve((size_t)128 * 256 * 2);
    (void)ws_size;

    hipMemsetAsync(flag, 0, 4, stream);

    prep_kernel<<<2048, 256, 0, stream>>>(x, (const unsigned int*)er,
                                          Wl1, Wr1, Wl2, Wr2,
                                          xb, wc1, wc2, flag, ccnt, cfill);

    // CSR build: two-level partition with block-level reservation
    coarse_hist<<<512, 256, 0, stream>>>(er, flag, ccnt, E);
    coarse_scan<<<1, 256, 0, stream>>>(ccnt, coff, offsets, E);
    coarse_scatter2<<<CSB, 256, 0, stream>>>(er, flag, coff, cfill, pbuf, E);
    fine_bucket<<<NBUCK, 512, 0, stream>>>(pbuf, coff, offsets, srcs_sort, N);

    const int fb = N / 32;                                   // 3125 (N % 32 == 0)

    // layer 1 (fused aggregate + linear, relu, bf16 out)
    sage_fused<64, true, true><<<fb, 256, 0, stream>>>(offsets, srcs_sort, xb, wc1, bl1, hb, N);
    // layer 2 (fused aggregate + linear, f32 out)
    sage_fused<128, false, false><<<fb, 256, 0, stream>>>(offsets, srcs_sort, hb, wc2, bl2, out, N);
}

// Round 15
// 186.636 us; speedup vs baseline: 1.5724x; 1.1019x over previous
//
#include <hip/hip_runtime.h>
#include <hip/hip_bf16.h>
#include <stdint.h>

#define NN 100000
#define EE 1600000
#define NBUCK 196              // ceil(NN/512): buckets of 512 dst nodes
#define CSB 512                // scatter blocks
#define CAP 12288              // fixed bucket stride (avg 8192, max ~8600)

typedef __attribute__((ext_vector_type(4))) float f32x4;
typedef __attribute__((ext_vector_type(8))) short bf16x8;

__device__ inline ushort f2bf(float f) {
    union { float f; uint32_t u; } v; v.f = f;
    uint32_t u = v.u;
    uint32_t r = (u + 0x7fffu + ((u >> 16) & 1u)) >> 16;   // RNE
    return (ushort)r;
}
__device__ inline float bflo(uint32_t u) {
    union { uint32_t u; float f; } v; v.u = u << 16; return v.f;
}
__device__ inline float bfhi(uint32_t u) {
    union { uint32_t u; float f; } v; v.u = u & 0xffff0000u; return v.f;
}

// ---------------- prep: bf16 conversions + zero bucket counters ----------------
__global__ __launch_bounds__(256) void prep_kernel(
    const float* __restrict__ x,
    const float* __restrict__ Wl1, const float* __restrict__ Wr1,
    const float* __restrict__ Wl2, const float* __restrict__ Wr2,
    ushort* __restrict__ xb, ushort* __restrict__ wc1, ushort* __restrict__ wc2,
    int* __restrict__ cfill)
{
    const int gid = blockIdx.x * 256 + threadIdx.x;
    const int stride = gridDim.x * 256;

    if (gid < NBUCK) cfill[gid] = 0;

    const int n4 = NN * 64 / 4;
    for (int i = gid; i < n4; i += stride) {
        float4 v = *(const float4*)&x[i * 4];
        ushort o[4] = { f2bf(v.x), f2bf(v.y), f2bf(v.z), f2bf(v.w) };
        *(uint64_t*)&xb[i * 4] = *(const uint64_t*)o;
    }
    for (int i = gid; i < 128 * 128; i += stride) {
        int o = i >> 7, k = i & 127;
        float v = (k < 64) ? Wl1[o * 64 + k] : Wr1[o * 64 + (k - 64)];
        wc1[o * 128 + k] = f2bf(v);
    }
    for (int i = gid; i < 128 * 256; i += stride) {
        int o = i >> 8, k = i & 255;
        float v = (k < 128) ? Wl2[o * 128 + k] : Wr2[o * 128 + (k - 128)];
        wc2[o * 256 + k] = f2bf(v);
    }
}

// ---------------- single-pass scatter into fixed-stride buckets ----------------
// Per-block local dtype detect (int64 hi-words of own chunk all zero), LDS hist,
// ONE global atomic per (block,bucket), dense packed writes at b*CAP + base.
__global__ __launch_bounds__(256) void scatter_fixed(const void* raw, int* cfill,
                                                     uint32_t* pbuf, int E) {
    __shared__ int lh[NBUCK];
    __shared__ int gbase[NBUCK];
    __shared__ int lfill[NBUCK];
    __shared__ int is64;
    const int t = threadIdx.x;
    for (int i = t; i < NBUCK; i += 256) { lh[i] = 0; lfill[i] = 0; }
    if (t == 0) is64 = 1;
    __syncthreads();
    const int chunk = (E + (int)gridDim.x - 1) / (int)gridDim.x;
    const int s0 = blockIdx.x * chunk;
    const int s1 = min(E, s0 + chunk);
    if (t < 64 && s0 + t < E) {
        if (((const unsigned int*)raw)[2 * (s0 + t) + 1] != 0u) atomicAnd(&is64, 0);
    }
    __syncthreads();
    const bool i64 = (is64 != 0);
    if (i64) {
        const long long* p = (const long long*)raw;
        for (int e = s0 + t; e < s1; e += 256) atomicAdd(&lh[((int)p[E + e]) >> 9], 1);
    } else {
        const int* p = (const int*)raw;
        for (int e = s0 + t; e < s1; e += 256) atomicAdd(&lh[p[E + e] >> 9], 1);
    }
    __syncthreads();
    for (int i = t; i < NBUCK; i += 256)
        gbase[i] = i * CAP + (lh[i] ? atomicAdd(&cfill[i], lh[i]) : 0);
    __syncthreads();
    if (i64) {
        const long long* p = (const long long*)raw;
        for (int e = s0 + t; e < s1; e += 256) {
            int sr = (int)p[e], d = (int)p[E + e];
            int b = d >> 9;
            int r = atomicAdd(&lfill[b], 1);
            pbuf[gbase[b] + r] = ((uint32_t)(d & 511) << 17) | (uint32_t)sr;
        }
    } else {
        const int* p = (const int*)raw;
        for (int e = s0 + t; e < s1; e += 256) {
            int sr = p[e], d = p[E + e];
            int b = d >> 9;
            int r = atomicAdd(&lfill[b], 1);
            pbuf[gbase[b] + r] = ((uint32_t)(d & 511) << 17) | (uint32_t)sr;
        }
    }
}

// ---------------- tiny scan: bucket counts -> compact bucket bases ----------------
__global__ void bucket_scan(const int* __restrict__ cfill, int* __restrict__ coff,
                            int* __restrict__ offsets, int E) {
    __shared__ int part[256];
    int t = threadIdx.x;
    int v = (t < NBUCK) ? cfill[t] : 0;
    part[t] = v; __syncthreads();
    for (int off = 1; off < 256; off <<= 1) {
        int add = (t >= off) ? part[t - off] : 0;
        __syncthreads();
        part[t] += add;
        __syncthreads();
    }
    if (t < NBUCK) coff[t] = part[t] - v;        // exclusive
    if (t == 0) { coff[NBUCK] = E; offsets[NN] = E; }
}

// ---------------- fine bucket: strided pbuf -> per-node offsets + compact srcs ----
__global__ __launch_bounds__(512) void fine_bucket(const uint32_t* __restrict__ pbuf,
                                                   const int* __restrict__ cfill,
                                                   const int* __restrict__ coff,
                                                   int* __restrict__ offsets,
                                                   int* __restrict__ srcs_sort, int N) {
    __shared__ int cnt[512], sc[512], fil[512];
    const int b = blockIdx.x, t = threadIdx.x;
    const int base = b * CAP;
    const int m = cfill[b];
    const int s = coff[b];
    cnt[t] = 0; fil[t] = 0;
    __syncthreads();
    for (int i = t; i < m; i += 512) atomicAdd(&cnt[pbuf[base + i] >> 17], 1);
    __syncthreads();
    sc[t] = cnt[t];
    __syncthreads();
    for (int off = 1; off < 512; off <<= 1) {
        int add = (t >= off) ? sc[t - off] : 0;
        __syncthreads();
        sc[t] += add;
        __syncthreads();
    }
    const int nb0 = b * 512;
    if (nb0 + t < N) offsets[nb0 + t] = s + sc[t] - cnt[t];
    for (int i = t; i < m; i += 512) {
        uint32_t p = pbuf[base + i];
        int dl = (int)(p >> 17);
        int pos = s + (sc[dl] - cnt[dl]) + atomicAdd(&fil[dl], 1);
        srcs_sort[pos] = (int)(p & 0x1FFFFu);
    }
}

// ---------------- FUSED aggregate + SAGE linear (unchanged from R14) ----------------
template<int K, bool RELU, bool OUT_BF16>
__global__ __launch_bounds__(256, 8) void sage_fused(
    const int* __restrict__ offsets, const int* __restrict__ srcs,
    const ushort* __restrict__ xin, const ushort* __restrict__ Wcat,
    const float* __restrict__ bl, void* __restrict__ outv, int N)
{
    constexpr int KT = 2 * K;
    constexpr int RP = K + 8;                 // padded row (ushorts)
    __shared__ ushort mlds[32][RP];
    const int t = threadIdx.x;
    const int w = t >> 6;
    const int lane = t & 63;
    const int nb = blockIdx.x * 32;

    const int q     = lane >> 4;              // quarter 0-3
    const int ql    = lane & 15;
    const int qbase = lane & 48;              // shfl base of own quarter

    int offv = 0;
    if (lane < 9) offv = offsets[nb + w * 8 + lane];

    for (int pi = 0; pi < 2; pi++) {
        const int ln = w * 8 + pi * 4 + q;            // local node index
        const int s0 = __shfl(offv, pi * 4 + q);
        const int s1 = __shfl(offv, pi * 4 + q + 1);
        const float inv = 1.0f / fmaxf((float)(s1 - s0), 1.0f);

        if (K == 64) {
            float f0=0.f, f1=0.f, f2=0.f, f3=0.f;
            for (int base = s0; base < s1; base += 16) {
                int cnt = min(16, s1 - base);
                int myidx = (base + ql < s1) ? srcs[base + ql] : 0;
                int j = 0;
                for (; j + 4 <= cnt; j += 4) {
                    int sA = __shfl(myidx, qbase + j);
                    int sB = __shfl(myidx, qbase + j + 1);
                    int sC = __shfl(myidx, qbase + j + 2);
                    int sD = __shfl(myidx, qbase + j + 3);
                    uint2 uA = *(const uint2*)&xin[(size_t)sA * 64 + ql * 4];
                    uint2 uB = *(const uint2*)&xin[(size_t)sB * 64 + ql * 4];
                    uint2 uC = *(const uint2*)&xin[(size_t)sC * 64 + ql * 4];
                    uint2 uD = *(const uint2*)&xin[(size_t)sD * 64 + ql * 4];
                    f0 += bflo(uA.x); f1 += bfhi(uA.x); f2 += bflo(uA.y); f3 += bfhi(uA.y);
                    f0 += bflo(uB.x); f1 += bfhi(uB.x); f2 += bflo(uB.y); f3 += bfhi(uB.y);
                    f0 += bflo(uC.x); f1 += bfhi(uC.x); f2 += bflo(uC.y); f3 += bfhi(uC.y);
                    f0 += bflo(uD.x); f1 += bfhi(uD.x); f2 += bflo(uD.y); f3 += bfhi(uD.y);
                }
                for (; j < cnt; j++) {
                    int s = __shfl(myidx, qbase + j);
                    uint2 u = *(const uint2*)&xin[(size_t)s * 64 + ql * 4];
                    f0 += bflo(u.x); f1 += bfhi(u.x); f2 += bflo(u.y); f3 += bfhi(u.y);
                }
            }
            ushort o[4] = { f2bf(f0 * inv), f2bf(f1 * inv), f2bf(f2 * inv), f2bf(f3 * inv) };
            *(uint64_t*)&mlds[ln][ql * 4] = *(const uint64_t*)o;
        } else {
            float f0=0.f, f1=0.f, f2=0.f, f3=0.f, f4=0.f, f5=0.f, f6=0.f, f7=0.f;
            for (int base = s0; base < s1; base += 16) {
                int cnt = min(16, s1 - base);
                int myidx = (base + ql < s1) ? srcs[base + ql] : 0;
                int j = 0;
                for (; j + 4 <= cnt; j += 4) {
                    int sA = __shfl(myidx, qbase + j);
                    int sB = __shfl(myidx, qbase + j + 1);
                    int sC = __shfl(myidx, qbase + j + 2);
                    int sD = __shfl(myidx, qbase + j + 3);
                    uint4 uA = *(const uint4*)&xin[(size_t)sA * 128 + ql * 8];
                    uint4 uB = *(const uint4*)&xin[(size_t)sB * 128 + ql * 8];
                    uint4 uC = *(const uint4*)&xin[(size_t)sC * 128 + ql * 8];
                    uint4 uD = *(const uint4*)&xin[(size_t)sD * 128 + ql * 8];
                    f0 += bflo(uA.x); f1 += bfhi(uA.x); f2 += bflo(uA.y); f3 += bfhi(uA.y);
                    f4 += bflo(uA.z); f5 += bfhi(uA.z); f6 += bflo(uA.w); f7 += bfhi(uA.w);
                    f0 += bflo(uB.x); f1 += bfhi(uB.x); f2 += bflo(uB.y); f3 += bfhi(uB.y);
                    f4 += bflo(uB.z); f5 += bfhi(uB.z); f6 += bflo(uB.w); f7 += bfhi(uB.w);
                    f0 += bflo(uC.x); f1 += bfhi(uC.x); f2 += bflo(uC.y); f3 += bfhi(uC.y);
                    f4 += bflo(uC.z); f5 += bfhi(uC.z); f6 += bflo(uC.w); f7 += bfhi(uC.w);
                    f0 += bflo(uD.x); f1 += bfhi(uD.x); f2 += bflo(uD.y); f3 += bfhi(uD.y);
                    f4 += bflo(uD.z); f5 += bfhi(uD.z); f6 += bflo(uD.w); f7 += bfhi(uD.w);
                }
                for (; j < cnt; j++) {
                    int s = __shfl(myidx, qbase + j);
                    uint4 u = *(const uint4*)&xin[(size_t)s * 128 + ql * 8];
                    f0 += bflo(u.x); f1 += bfhi(u.x); f2 += bflo(u.y); f3 += bfhi(u.y);
                    f4 += bflo(u.z); f5 += bfhi(u.z); f6 += bflo(u.w); f7 += bfhi(u.w);
                }
            }
            ushort o[8] = { f2bf(f0 * inv), f2bf(f1 * inv), f2bf(f2 * inv), f2bf(f3 * inv),
                            f2bf(f4 * inv), f2bf(f5 * inv), f2bf(f6 * inv), f2bf(f7 * inv) };
            *(uint4*)&mlds[ln][ql * 8] = *(const uint4*)o;
        }
    }
    __syncthreads();

    // phase 2: GEMM 32 nodes x 128 channels; wave w owns channels w*32..w*32+31
    const int lrow = lane & 15;
    const int lgrp = lane >> 4;
    f32x4 acc[2][2];
    #pragma unroll
    for (int nt = 0; nt < 2; nt++)
        #pragma unroll
        for (int ct = 0; ct < 2; ct++)
            acc[nt][ct] = (f32x4){0.f, 0.f, 0.f, 0.f};

    #pragma unroll
    for (int ks = 0; ks < KT; ks += 32) {
        bf16x8 x0, x1;
        if (ks < K) {                         // mean tile from LDS
            x0 = *(const bf16x8*)&mlds[lrow][ks + lgrp * 8];
            x1 = *(const bf16x8*)&mlds[16 + lrow][ks + lgrp * 8];
        } else {                              // self rows straight from global
            const int ac = ks - K;
            x0 = *(const bf16x8*)&xin[(size_t)(nb + lrow) * K + ac + lgrp * 8];
            x1 = *(const bf16x8*)&xin[(size_t)(nb + 16 + lrow) * K + ac + lgrp * 8];
        }
        bf16x8 wA = *(const bf16x8*)&Wcat[(size_t)(w * 32 + lrow) * KT + ks + lgrp * 8];
        bf16x8 wB = *(const bf16x8*)&Wcat[(size_t)(w * 32 + 16 + lrow) * KT + ks + lgrp * 8];
        acc[0][0] = __builtin_amdgcn_mfma_f32_16x16x32_bf16(wA, x0, acc[0][0], 0, 0, 0);
        acc[0][1] = __builtin_amdgcn_mfma_f32_16x16x32_bf16(wB, x0, acc[0][1], 0, 0, 0);
        acc[1][0] = __builtin_amdgcn_mfma_f32_16x16x32_bf16(wA, x1, acc[1][0], 0, 0, 0);
        acc[1][1] = __builtin_amdgcn_mfma_f32_16x16x32_bf16(wB, x1, acc[1][1], 0, 0, 0);
    }

    #pragma unroll
    for (int ct = 0; ct < 2; ct++) {
        const int ch0 = w * 32 + ct * 16 + lgrp * 4;
        float4 b4 = *(const float4*)&bl[ch0];
        #pragma unroll
        for (int nt = 0; nt < 2; nt++) {
            int n = nb + nt * 16 + lrow;
            float v0 = acc[nt][ct][0] + b4.x;
            float v1 = acc[nt][ct][1] + b4.y;
            float v2 = acc[nt][ct][2] + b4.z;
            float v3 = acc[nt][ct][3] + b4.w;
            if (RELU) {
                v0 = fmaxf(v0, 0.f); v1 = fmaxf(v1, 0.f);
                v2 = fmaxf(v2, 0.f); v3 = fmaxf(v3, 0.f);
            }
            if (OUT_BF16) {
                ushort o[4] = { f2bf(v0), f2bf(v1), f2bf(v2), f2bf(v3) };
                *(uint64_t*)&((ushort*)outv)[(size_t)n * 128 + ch0] = *(const uint64_t*)o;
            } else {
                float4 o = make_float4(v0, v1, v2, v3);
                *(float4*)&((float*)outv)[(size_t)n * 128 + ch0] = o;
            }
        }
    }
}

// ---------------- launch ----------------
extern "C" void kernel_launch(void* const* d_in, const int* in_sizes, int n_in,
                              void* d_out, int out_size, void* d_ws, size_t ws_size,
                              hipStream_t stream) {
    const float* x   = (const float*)d_in[0];
    const void*  er  = d_in[1];
    const float* Wl1 = (const float*)d_in[2];
    const float* bl1 = (const float*)d_in[3];
    const float* Wr1 = (const float*)d_in[4];
    const float* Wl2 = (const float*)d_in[5];
    const float* bl2 = (const float*)d_in[6];
    const float* Wr2 = (const float*)d_in[7];
    float* out = (float*)d_out;

    const int N = NN, E = EE;

    // workspace carve-up (512B aligned)
    char* ws = (char*)d_ws;
    size_t off = 0;
    auto carve = [&](size_t bytes) { char* p = ws + off; off += (bytes + 511) & ~(size_t)511; return p; };
    int*      cfill     = (int*)     carve((size_t)NBUCK * 4);
    int*      coff      = (int*)     carve((size_t)(NBUCK + 1) * 4);
    uint32_t* pbuf      = (uint32_t*)carve((size_t)NBUCK * CAP * 4);
    int*      offsets   = (int*)     carve((size_t)(N + 1) * 4);
    int*      srcs_sort = (int*)     carve((size_t)E * 4);
    ushort*   xb        = (ushort*)  carve((size_t)N * 64 * 2);
    ushort*   hb        = (ushort*)  carve((size_t)N * 128 * 2);
    ushort*   wc1       = (ushort*)  carve((size_t)128 * 128 * 2);
    ushort*   wc2       = (ushort*)  carve((size_t)128 * 256 * 2);
    (void)ws_size;

    prep_kernel<<<2048, 256, 0, stream>>>(x, Wl1, Wr1, Wl2, Wr2, xb, wc1, wc2, cfill);

    scatter_fixed<<<CSB, 256, 0, stream>>>(er, cfill, pbuf, E);
    bucket_scan<<<1, 256, 0, stream>>>(cfill, coff, offsets, E);
    fine_bucket<<<NBUCK, 512, 0, stream>>>(pbuf, cfill, coff, offsets, srcs_sort, N);

    const int fb = N / 32;                                   // 3125 (N % 32 == 0)

    // layer 1 (fused aggregate + linear, relu, bf16 out)
    sage_fused<64, true, true><<<fb, 256, 0, stream>>>(offsets, srcs_sort, xb, wc1, bl1, hb, N);
    // layer 2 (fused aggregate + linear, f32 out)
    sage_fused<128, false, false><<<fb, 256, 0, stream>>>(offsets, srcs_sort, hb, wc2, bl2, out, N);
}